// Round 6
// baseline (160.224 us; speedup 1.0000x reference)
//
#include <hip/hip_runtime.h>
#include <math.h>

#define HH 352
#define WW 352
#define KW 8                       // burst window radius
constexpr float INFV = 1e10f;      // reference's stand-in for +inf
constexpr float BIGF = 3e38f;      // invalid-candidate sentinel (BIGF+sq -> inf, fmin ignores)

// ---------------------------------------------------------------------------
// Kernel 1: column pass, one thread per pixel. Nearest-opposite scan along the
// column, done as a BRANCH-FREE burst of 2*KW independent clamped loads
// (coalesced across lanes, all in flight simultaneously), with a rare exact
// serial fallback (P ~ 2^-16/pixel for random data; exact for any input).
// Also zero-initializes mm / acc / cnt used by later kernels.
// ---------------------------------------------------------------------------
__global__ __launch_bounds__(256) void col_win_kernel(const float* __restrict__ target,
                                                      float* __restrict__ gF,
                                                      float* __restrict__ gB,
                                                      unsigned int* __restrict__ mm,
                                                      double* __restrict__ acc,
                                                      unsigned int* __restrict__ cnt, int B)
{
    int idx = blockIdx.x * 256 + threadIdx.x;
    if (blockIdx.x == 0) {
        if (threadIdx.x < 2 * B)
            mm[threadIdx.x] = (threadIdx.x & 1) ? 0u : 0x7f800000u;  // min=+inf, max=0
        if (threadIdx.x == 0) { *acc = 0.0; *cnt = 0u; }
    }

    const int HW = HH * WW;
    int b = idx / HW;
    int r = idx - b * HW;
    int i = r / WW;                    // row within image

    bool fg = (target[idx] != 0.0f);

    int kh = 1 << 20;                  // nearest opposite distance (col)
    #pragma unroll
    for (int k = 1; k <= KW; ++k) {
        int iu = i - k, id = i + k;
        // clamped (always-valid) addresses -> unconditional independent loads
        float vu = target[idx - (iu >= 0 ? k : 0) * WW];
        float vd = target[idx + (id < HH ? k : 0) * WW];
        bool ou = (iu >= 0) && ((vu != 0.0f) != fg);
        bool od = (id < HH) && ((vd != 0.0f) != fg);
        if ((ou || od) && k < kh) kh = k;          // cndmask, no branch
    }
    if (kh == (1 << 20)) {             // rare exact fallback
        for (int k = KW + 1; k < HH; ++k) {
            int iu = i - k, id = i + k;
            bool hit = false;
            if (iu >= 0) hit = ((target[idx - k * WW] != 0.0f) != fg);
            if (!hit && id < HH) hit = ((target[idx + k * WW] != 0.0f) != fg);
            if (hit) { kh = k; break; }
            if (iu < 0 && id >= HH) break;
        }
    }
    float dsq = (kh == (1 << 20)) ? INFV : (float)(kh * kh);
    gF[idx] = fg ? 0.0f : dsq;
    gB[idx] = fg ? dsq : 0.0f;
}

// ---------------------------------------------------------------------------
// Kernel 2: row min-plus pass, one thread per pixel. Burst-loads the +-KW
// neighborhood of both maps (independent coalesced loads), branchless min,
// then the exact windowed serial loop only for unsettled lanes (~1e-4).
// fminf(fl,fr)+sq == fminf(fl+sq, fr+sq): f32 add is monotone -> exact.
// Then sdt -> w -> store + per-sample min/max atomics.
// ---------------------------------------------------------------------------
__global__ __launch_bounds__(256) void row_win_kernel(const float* __restrict__ gF,
                                                      const float* __restrict__ gB,
                                                      float* __restrict__ Wm,
                                                      unsigned int* __restrict__ mm)
{
    const int HW = HH * WW;
    int idx = blockIdx.x * 256 + threadIdx.x;
    int b = idx / HW;
    int r = idx - b * HW;
    int i = r / WW;
    int j = r - i * WW;
    int rb = idx - j;                  // row base index

    float bF = gF[idx];
    float bB = gB[idx];
    #pragma unroll
    for (int k = 1; k <= KW; ++k) {
        float sq = (float)(k * k);
        int jl = j - k, jr = j + k;
        int jlc = jl >= 0 ? jl : 0;
        int jrc = jr < WW ? jr : WW - 1;
        float fl = gF[rb + jlc], bl = gB[rb + jlc];
        float fr = gF[rb + jrc], br = gB[rb + jrc];
        if (jl < 0)   { fl = BIGF; bl = BIGF; }
        if (jr >= WW) { fr = BIGF; br = BIGF; }
        bF = fminf(bF, fminf(fl, fr) + sq);
        bB = fminf(bB, fminf(bl, br) + sq);
    }
    // exact fallback; first iteration's stop test covers the common case
    for (int k = KW + 1; k < WW; ++k) {
        float sq = (float)(k * k);
        if (sq >= bF && sq >= bB) break;
        int jl = j - k, jr = j + k;
        if (jl >= 0) {
            bF = fminf(bF, gF[rb + jl] + sq);
            bB = fminf(bB, gB[rb + jl] + sq);
        }
        if (jr < WW) {
            bF = fminf(bF, gF[rb + jr] + sq);
            bB = fminf(bB, gB[rb + jr] + sq);
        }
        if (jl < 0 && jr >= WW) break;
    }

    float sdt = sqrtf(bB) - sqrtf(bF);            // sign irrelevant: |sdt| below
    float w = expf(-fabsf(sdt) * 0.2f);           // SIGMA = 5
    Wm[idx] = w;

    // block min/max reduce (b is uniform per block: HW % 256 == 0)
    __shared__ float smin[256];
    __shared__ float smax[256];
    smin[threadIdx.x] = w;
    smax[threadIdx.x] = w;
    __syncthreads();
    for (int s = 128; s > 0; s >>= 1) {
        if (threadIdx.x < s) {
            smin[threadIdx.x] = fminf(smin[threadIdx.x], smin[threadIdx.x + s]);
            smax[threadIdx.x] = fmaxf(smax[threadIdx.x], smax[threadIdx.x + s]);
        }
        __syncthreads();
    }
    if (threadIdx.x == 0) {
        // w > 0 so float ordering == uint ordering on the raw bits
        atomicMin(&mm[2 * b],     __float_as_uint(smin[0]));
        atomicMax(&mm[2 * b + 1], __float_as_uint(smax[0]));
    }
}

// ---------------------------------------------------------------------------
// Kernel 3 (fused 3+4): BCE-with-logits * (1 + 0.5*normalized w), block sum,
// f64 atomicAdd into acc; last finished block writes the mean to d_out.
// ---------------------------------------------------------------------------
__global__ __launch_bounds__(256) void loss_kernel(const float* __restrict__ pred,
                                                   const float* __restrict__ target,
                                                   const float* __restrict__ Wm,
                                                   const unsigned int* __restrict__ mm,
                                                   double* __restrict__ acc,
                                                   unsigned int* __restrict__ cnt,
                                                   float* __restrict__ out,
                                                   int nBlk, double invN)
{
    const int HW = HH * WW;
    int idx = blockIdx.x * 256 + threadIdx.x;
    int b = idx / HW;
    float wmin = __uint_as_float(mm[2 * b]);
    float wmax = __uint_as_float(mm[2 * b + 1]);
    float p = pred[idx];
    float t = target[idx];
    float w = Wm[idx];
    float wn = (w - wmin) / (wmax - wmin + 1e-6f);
    float bce = fmaxf(p, 0.0f) - p * t + log1pf(expf(-fabsf(p)));
    float v = bce * (1.0f + 0.5f * wn);

    __shared__ float ssum[256];
    ssum[threadIdx.x] = v;
    __syncthreads();
    for (int s = 128; s > 0; s >>= 1) {
        if (threadIdx.x < s) ssum[threadIdx.x] += ssum[threadIdx.x + s];
        __syncthreads();
    }
    if (threadIdx.x == 0) {
        atomicAdd(acc, (double)ssum[0]);
        __threadfence();                               // device-scope: adds visible
        unsigned int old = atomicAdd(cnt, 1u);
        if (old == (unsigned int)(nBlk - 1)) {
            double total = atomicAdd(acc, 0.0);        // atomic read of final sum
            out[0] = (float)(total * invN);
        }
    }
}

extern "C" void kernel_launch(void* const* d_in, const int* in_sizes, int n_in,
                              void* d_out, int out_size, void* d_ws, size_t ws_size,
                              hipStream_t stream)
{
    const float* pred   = (const float*)d_in[0];
    const float* target = (const float*)d_in[1];
    float* out = (float*)d_out;

    const int N = in_sizes[0];           // B*1*H*W
    const int B = N / (HH * WW);         // = 4

    float* gF = (float*)d_ws;
    float* gB = gF + N;
    float* Wm = gB + N;
    unsigned int* mm = (unsigned int*)(Wm + N);       // 2B u32 (8 entries)
    double* acc = (double*)(mm + 8);                  // 8-byte aligned (3N*4 % 8 == 0)
    unsigned int* cnt = (unsigned int*)(acc + 1);

    int nBlk = N / 256;                  // 1936, exact

    // 1) column burst-window EDT pass (both maps) + mm/acc/cnt init
    hipLaunchKernelGGL(col_win_kernel, dim3(nBlk), dim3(256), 0, stream,
                       target, gF, gB, mm, acc, cnt, B);

    // 2) row burst-window min-plus pass + w + per-sample min/max
    hipLaunchKernelGGL(row_win_kernel, dim3(nBlk), dim3(256), 0, stream,
                       gF, gB, Wm, mm);

    // 3) fused weighted-BCE sum + last-block mean write
    hipLaunchKernelGGL(loss_kernel, dim3(nBlk), dim3(256), 0, stream,
                       pred, target, Wm, mm, acc, cnt, out, nBlk, 1.0 / (double)N);
}

// Round 7
// 78.318 us; speedup vs baseline: 2.0458x; 2.0458x over previous
//
#include <hip/hip_runtime.h>
#include <math.h>

#define HH 352
#define WW 352
#define KW 8                       // burst window radius
constexpr float INFV = 1e10f;      // reference's stand-in for +inf
constexpr float BIGF = 3e38f;      // invalid-candidate sentinel (never wins the min)

// ---------------------------------------------------------------------------
// Kernel 1: column pass, one thread per pixel. Nearest-opposite scan along the
// column as a branch-free burst of 2*KW independent clamped loads (coalesced
// across lanes, all in flight at once), plus a rare exact serial fallback
// (P ~ 2^-16 per pixel for random data; exact for any input).
// ---------------------------------------------------------------------------
__global__ __launch_bounds__(256) void col_win_kernel(const float* __restrict__ target,
                                                      float* __restrict__ gF,
                                                      float* __restrict__ gB)
{
    int idx = blockIdx.x * 256 + threadIdx.x;
    const int HW = HH * WW;
    int b = idx / HW;
    int r = idx - b * HW;
    int i = r / WW;                    // row within image

    bool fg = (target[idx] != 0.0f);

    int kh = 1 << 20;                  // nearest opposite distance (col)
    #pragma unroll
    for (int k = 1; k <= KW; ++k) {
        int iu = i - k, id = i + k;
        // clamped (always-valid) addresses -> unconditional independent loads
        float vu = target[idx - (iu >= 0 ? k : 0) * WW];
        float vd = target[idx + (id < HH ? k : 0) * WW];
        bool ou = (iu >= 0) && ((vu != 0.0f) != fg);
        bool od = (id < HH) && ((vd != 0.0f) != fg);
        if ((ou || od) && k < kh) kh = k;          // cndmask, no branch
    }
    if (kh == (1 << 20)) {             // rare exact fallback
        for (int k = KW + 1; k < HH; ++k) {
            int iu = i - k, id = i + k;
            bool hit = false;
            if (iu >= 0) hit = ((target[idx - k * WW] != 0.0f) != fg);
            if (!hit && id < HH) hit = ((target[idx + k * WW] != 0.0f) != fg);
            if (hit) { kh = k; break; }
            if (iu < 0 && id >= HH) break;
        }
    }
    float dsq = (kh == (1 << 20)) ? INFV : (float)(kh * kh);
    gF[idx] = fg ? 0.0f : dsq;
    gB[idx] = fg ? dsq : 0.0f;
}

// ---------------------------------------------------------------------------
// Kernel 2: row min-plus pass, one thread per pixel. Burst-loads the +-KW
// neighborhood of both maps (independent coalesced loads), branchless min,
// exact serial fallback only for unsettled lanes. Then sdt -> w -> store.
// Per-block min/max go to PLAIN arrays pmin/pmax (no atomics).
// ---------------------------------------------------------------------------
__global__ __launch_bounds__(256) void row_win_kernel(const float* __restrict__ gF,
                                                      const float* __restrict__ gB,
                                                      float* __restrict__ Wm,
                                                      float* __restrict__ pmin,
                                                      float* __restrict__ pmax)
{
    const int HW = HH * WW;
    int idx = blockIdx.x * 256 + threadIdx.x;
    int b = idx / HW;
    int r = idx - b * HW;
    int i = r / WW;
    int j = r - i * WW;
    int rb = idx - j;                  // row base index

    float bF = gF[idx];
    float bB = gB[idx];
    #pragma unroll
    for (int k = 1; k <= KW; ++k) {
        float sq = (float)(k * k);
        int jl = j - k, jr = j + k;
        int jlc = jl >= 0 ? jl : 0;
        int jrc = jr < WW ? jr : WW - 1;
        float fl = gF[rb + jlc], bl = gB[rb + jlc];
        float fr = gF[rb + jrc], br = gB[rb + jrc];
        if (jl < 0)   { fl = BIGF; bl = BIGF; }
        if (jr >= WW) { fr = BIGF; br = BIGF; }
        // fmin(fl,fr)+sq == fmin(fl+sq,fr+sq): f32 add is monotone -> exact
        bF = fminf(bF, fminf(fl, fr) + sq);
        bB = fminf(bB, fminf(bl, br) + sq);
    }
    for (int k = KW + 1; k < WW; ++k) {        // exact fallback (rarely iterates)
        float sq = (float)(k * k);
        if (sq >= bF && sq >= bB) break;
        int jl = j - k, jr = j + k;
        if (jl >= 0) {
            bF = fminf(bF, gF[rb + jl] + sq);
            bB = fminf(bB, gB[rb + jl] + sq);
        }
        if (jr < WW) {
            bF = fminf(bF, gF[rb + jr] + sq);
            bB = fminf(bB, gB[rb + jr] + sq);
        }
        if (jl < 0 && jr >= WW) break;
    }

    float sdt = sqrtf(bB) - sqrtf(bF);            // sign irrelevant: |sdt| below
    float w = expf(-fabsf(sdt) * 0.2f);           // SIGMA = 5
    Wm[idx] = w;

    __shared__ float smin[256];
    __shared__ float smax[256];
    smin[threadIdx.x] = w;
    smax[threadIdx.x] = w;
    __syncthreads();
    for (int s = 128; s > 0; s >>= 1) {
        if (threadIdx.x < s) {
            smin[threadIdx.x] = fminf(smin[threadIdx.x], smin[threadIdx.x + s]);
            smax[threadIdx.x] = fmaxf(smax[threadIdx.x], smax[threadIdx.x + s]);
        }
        __syncthreads();
    }
    if (threadIdx.x == 0) {
        pmin[blockIdx.x] = smin[0];               // plain stores — no atomics
        pmax[blockIdx.x] = smax[0];
    }
}

// ---------------------------------------------------------------------------
// Kernel 3: loss pass. Each block first reduces its sample's 484 per-block
// min/max entries (L2-resident, 2 loads/thread), then computes
// BCE * (1 + 0.5 * normalized w) and stores a plain per-block partial sum.
// ---------------------------------------------------------------------------
__global__ __launch_bounds__(256) void loss_kernel(const float* __restrict__ pred,
                                                   const float* __restrict__ target,
                                                   const float* __restrict__ Wm,
                                                   const float* __restrict__ pmin,
                                                   const float* __restrict__ pmax,
                                                   float* __restrict__ partials)
{
    const int HW = HH * WW;
    const int BPS = HW / 256;                     // blocks per sample = 484
    int idx = blockIdx.x * 256 + threadIdx.x;
    int b = blockIdx.x / BPS;                     // block-uniform sample id

    __shared__ float smin[256];
    __shared__ float smax[256];
    float lmin = INFINITY, lmax = 0.0f;
    for (int t = threadIdx.x; t < BPS; t += 256) {
        lmin = fminf(lmin, pmin[b * BPS + t]);
        lmax = fmaxf(lmax, pmax[b * BPS + t]);
    }
    smin[threadIdx.x] = lmin;
    smax[threadIdx.x] = lmax;
    __syncthreads();
    for (int s = 128; s > 0; s >>= 1) {
        if (threadIdx.x < s) {
            smin[threadIdx.x] = fminf(smin[threadIdx.x], smin[threadIdx.x + s]);
            smax[threadIdx.x] = fmaxf(smax[threadIdx.x], smax[threadIdx.x + s]);
        }
        __syncthreads();
    }
    float wmin = smin[0];
    float wmax = smax[0];
    __syncthreads();                              // before reusing smin as sum buf

    float p = pred[idx];
    float t = target[idx];
    float w = Wm[idx];
    float wn = (w - wmin) / (wmax - wmin + 1e-6f);
    float bce = fmaxf(p, 0.0f) - p * t + log1pf(expf(-fabsf(p)));
    float v = bce * (1.0f + 0.5f * wn);

    smin[threadIdx.x] = v;
    __syncthreads();
    for (int s = 128; s > 0; s >>= 1) {
        if (threadIdx.x < s) smin[threadIdx.x] += smin[threadIdx.x + s];
        __syncthreads();
    }
    if (threadIdx.x == 0) partials[blockIdx.x] = smin[0];
}

// ---------------------------------------------------------------------------
// Kernel 4: final reduction (double accumulation) -> mean -> d_out[0]
// ---------------------------------------------------------------------------
__global__ __launch_bounds__(256) void final_kernel(const float* __restrict__ partials,
                                                    float* __restrict__ out,
                                                    int nPart, double invN)
{
    __shared__ double s[256];
    double acc = 0.0;
    for (int i = threadIdx.x; i < nPart; i += 256) acc += (double)partials[i];
    s[threadIdx.x] = acc;
    __syncthreads();
    for (int st = 128; st > 0; st >>= 1) {
        if (threadIdx.x < st) s[threadIdx.x] += s[threadIdx.x + st];
        __syncthreads();
    }
    if (threadIdx.x == 0) out[0] = (float)(s[0] * invN);
}

extern "C" void kernel_launch(void* const* d_in, const int* in_sizes, int n_in,
                              void* d_out, int out_size, void* d_ws, size_t ws_size,
                              hipStream_t stream)
{
    const float* pred   = (const float*)d_in[0];
    const float* target = (const float*)d_in[1];
    float* out = (float*)d_out;

    const int N = in_sizes[0];           // B*1*H*W = 495616

    float* gF = (float*)d_ws;
    float* gB = gF + N;
    float* Wm = gB + N;
    int nBlk = N / 256;                  // 1936, exact
    float* pmin = Wm + N;
    float* pmax = pmin + nBlk;
    float* partials = pmax + nBlk;

    // 1) column burst-window EDT pass (both maps)
    hipLaunchKernelGGL(col_win_kernel, dim3(nBlk), dim3(256), 0, stream,
                       target, gF, gB);

    // 2) row burst-window min-plus pass + w + per-block min/max (plain stores)
    hipLaunchKernelGGL(row_win_kernel, dim3(nBlk), dim3(256), 0, stream,
                       gF, gB, Wm, pmin, pmax);

    // 3) per-sample minmax reduce (from L2) + weighted BCE partial sums
    hipLaunchKernelGGL(loss_kernel, dim3(nBlk), dim3(256), 0, stream,
                       pred, target, Wm, pmin, pmax, partials);

    // 4) final mean
    hipLaunchKernelGGL(final_kernel, dim3(1), dim3(256), 0, stream,
                       partials, out, nBlk, 1.0 / (double)N);
}

// Round 9
// 74.724 us; speedup vs baseline: 2.1442x; 1.0481x over previous
//
#include <hip/hip_runtime.h>
#include <math.h>

#define HH 352
#define WW 352
#define KW 8                       // burst window radius
#define BT 384                     // block threads (352 active, 6 waves)
#define NW (BT / 64)
constexpr float INFV = 1e10f;      // reference's stand-in for +inf
constexpr float BIGF = 3e38f;      // invalid-candidate sentinel

// ---------------------------------------------------------------------------
// Fused kernel: one block per image row (B*H blocks).
//  1) per-thread col-EDT via branch-free burst of 2*KW clamped coalesced
//     target loads (+ rare exact serial fallback) -> row's gF/gB in LDS
//  2) row min-plus from LDS (burst window + exact fallback; whole row is
//     in LDS so the fallback is exact and cheap)
//  3) w = exp(-|sqrt(bB)-sqrt(bF)|/5); bce from pred/target
//  4) block-reduce (min w, max w, sum bce, sum bce*w) -> 4 floats per row
// Loss separability: sum(bce*(1+0.5*wn)) = S1 + 0.5*(SW - wmin*S1)/den,
// so the per-pixel weight map never needs to be materialized.
// ---------------------------------------------------------------------------
__global__ __launch_bounds__(BT) void fused_kernel(const float* __restrict__ pred,
                                                   const float* __restrict__ target,
                                                   float* __restrict__ rmin,
                                                   float* __restrict__ rmax,
                                                   float* __restrict__ rs1,
                                                   float* __restrict__ rsw)
{
    const int row = blockIdx.x;            // = b*HH + i
    const int i = row % HH;                // row within image
    const int j = threadIdx.x;
    const bool act = (j < WW);
    const int base = row * WW;

    __shared__ float sF[WW];
    __shared__ float sB[WW];
    __shared__ float wred[4][NW];

    float w = 0.f, bce = 0.f, bw = 0.f;
    bool fg = false;

    if (act) {
        int idx = base + j;
        fg = (target[idx] != 0.0f);
        int kh = 1 << 20;                  // nearest-opposite col distance
        #pragma unroll
        for (int k = 1; k <= KW; ++k) {
            int iu = i - k, id = i + k;
            // clamped always-valid addresses -> independent coalesced loads
            float vu = target[idx - (iu >= 0 ? k : 0) * WW];
            float vd = target[idx + (id < HH ? k : 0) * WW];
            bool ou = (iu >= 0) && ((vu != 0.f) != fg);
            bool od = (id < HH) && ((vd != 0.f) != fg);
            if ((ou || od) && k < kh) kh = k;       // cndmask, no branch
        }
        if (kh == (1 << 20)) {             // rare exact fallback (P ~ 2^-16)
            for (int k = KW + 1; k < HH; ++k) {
                int iu = i - k, id = i + k;
                bool hit = false;
                if (iu >= 0) hit = ((target[idx - k * WW] != 0.f) != fg);
                if (!hit && id < HH) hit = ((target[idx + k * WW] != 0.f) != fg);
                if (hit) { kh = k; break; }
                if (iu < 0 && id >= HH) break;
            }
        }
        float dsq = (kh == (1 << 20)) ? INFV : (float)(kh * kh);
        sF[j] = fg ? 0.f : dsq;            // pass-1 value for dist_fg map
        sB[j] = fg ? dsq : 0.f;            // pass-1 value for dist_bg map
    }
    __syncthreads();

    if (act) {
        float bF = sF[j], bB = sB[j];
        #pragma unroll
        for (int k = 1; k <= KW; ++k) {    // burst window: independent LDS reads
            float sq = (float)(k * k);
            int jl = j - k, jr = j + k;
            float fl = (jl >= 0) ? sF[jl] : BIGF;
            float bl = (jl >= 0) ? sB[jl] : BIGF;
            float fr = (jr < WW) ? sF[jr] : BIGF;
            float br = (jr < WW) ? sB[jr] : BIGF;
            // fmin(fl,fr)+sq == fmin(fl+sq,fr+sq): f32 add is monotone -> exact
            bF = fminf(bF, fminf(fl, fr) + sq);
            bB = fminf(bB, fminf(bl, br) + sq);
        }
        for (int k = KW + 1; k < WW; ++k) {     // exact fallback, all in LDS
            float sq = (float)(k * k);
            if (sq >= bF && sq >= bB) break;
            int jl = j - k, jr = j + k;
            if (jl >= 0) { bF = fminf(bF, sF[jl] + sq); bB = fminf(bB, sB[jl] + sq); }
            if (jr < WW) { bF = fminf(bF, sF[jr] + sq); bB = fminf(bB, sB[jr] + sq); }
            if (jl < 0 && jr >= WW) break;
        }

        float sdt = sqrtf(bB) - sqrtf(bF);      // sign irrelevant: |sdt| below
        w = expf(-fabsf(sdt) * 0.2f);           // SIGMA = 5
        float p = pred[base + j];
        float t = fg ? 1.0f : 0.0f;             // target is exactly {0,1}
        bce = fmaxf(p, 0.f) - p * t + log1pf(expf(-fabsf(p)));
        bw = bce * w;
    }

    // block reduce: (min w, max w, sum bce, sum bce*w); inactive lanes neutral
    float lmin = act ? w : BIGF;
    float lmax = act ? w : 0.f;       // w > 0 always, so 0 is neutral for max
    float ls1 = bce;                  // 0 for inactive
    float lsw = bw;
    #pragma unroll
    for (int off = 32; off > 0; off >>= 1) {
        lmin = fminf(lmin, __shfl_down(lmin, off));
        lmax = fmaxf(lmax, __shfl_down(lmax, off));
        ls1 += __shfl_down(ls1, off);
        lsw += __shfl_down(lsw, off);
    }
    int wid = threadIdx.x >> 6;
    if ((threadIdx.x & 63) == 0) {
        wred[0][wid] = lmin; wred[1][wid] = lmax;
        wred[2][wid] = ls1;  wred[3][wid] = lsw;
    }
    __syncthreads();
    if (threadIdx.x == 0) {
        float m0 = wred[0][0], m1 = wred[1][0], s1 = wred[2][0], sw = wred[3][0];
        #pragma unroll
        for (int q = 1; q < NW; ++q) {
            m0 = fminf(m0, wred[0][q]);
            m1 = fmaxf(m1, wred[1][q]);
            s1 += wred[2][q];
            sw += wred[3][q];
        }
        rmin[row] = m0; rmax[row] = m1; rs1[row] = s1; rsw[row] = sw;
    }
}

// ---------------------------------------------------------------------------
// Final: single block. Per sample: reduce 352 row entries -> wmin, wmax,
// S1, SW (f64), combine loss_b = S1 + 0.5*(SW - wmin*S1)/den; mean -> out.
// ---------------------------------------------------------------------------
__global__ __launch_bounds__(256) void final_kernel(const float* __restrict__ rmin,
                                                    const float* __restrict__ rmax,
                                                    const float* __restrict__ rs1,
                                                    const float* __restrict__ rsw,
                                                    float* __restrict__ out,
                                                    int B, double invN)
{
    __shared__ float red1[256];
    __shared__ float red2[256];
    __shared__ double red3[256];
    __shared__ double red4[256];
    double total = 0.0;
    for (int b = 0; b < B; ++b) {
        float lmin = BIGF, lmax = 0.f;
        double s1 = 0.0, sw = 0.0;
        for (int t = threadIdx.x; t < HH; t += 256) {
            int o = b * HH + t;
            lmin = fminf(lmin, rmin[o]);
            lmax = fmaxf(lmax, rmax[o]);
            s1 += (double)rs1[o];
            sw += (double)rsw[o];
        }
        red1[threadIdx.x] = lmin; red2[threadIdx.x] = lmax;
        red3[threadIdx.x] = s1;   red4[threadIdx.x] = sw;
        __syncthreads();
        for (int s = 128; s > 0; s >>= 1) {
            if (threadIdx.x < s) {
                red1[threadIdx.x] = fminf(red1[threadIdx.x], red1[threadIdx.x + s]);
                red2[threadIdx.x] = fmaxf(red2[threadIdx.x], red2[threadIdx.x + s]);
                red3[threadIdx.x] += red3[threadIdx.x + s];
                red4[threadIdx.x] += red4[threadIdx.x + s];
            }
            __syncthreads();
        }
        if (threadIdx.x == 0) {
            double wmin = (double)red1[0];
            double den  = (double)red2[0] - wmin + 1e-6;
            total += red3[0] + 0.5 * (red4[0] - wmin * red3[0]) / den;
        }
        __syncthreads();    // before next iteration reuses red arrays
    }
    if (threadIdx.x == 0) out[0] = (float)(total * invN);
}

extern "C" void kernel_launch(void* const* d_in, const int* in_sizes, int n_in,
                              void* d_out, int out_size, void* d_ws, size_t ws_size,
                              hipStream_t stream)
{
    const float* pred   = (const float*)d_in[0];
    const float* target = (const float*)d_in[1];
    float* out = (float*)d_out;

    const int N = in_sizes[0];           // B*1*H*W = 495616
    const int B = N / (HH * WW);         // = 4
    const int nRows = B * HH;            // 1408

    float* rmin = (float*)d_ws;
    float* rmax = rmin + nRows;
    float* rs1  = rmax + nRows;
    float* rsw  = rs1 + nRows;

    // 1) fused col-EDT + row min-plus + w + bce + per-row reduce
    hipLaunchKernelGGL(fused_kernel, dim3(nRows), dim3(BT), 0, stream,
                       pred, target, rmin, rmax, rs1, rsw);

    // 2) per-sample combine + mean
    hipLaunchKernelGGL(final_kernel, dim3(1), dim3(256), 0, stream,
                       rmin, rmax, rs1, rsw, out, B, 1.0 / (double)N);
}

// Round 10
// 66.369 us; speedup vs baseline: 2.4142x; 1.1259x over previous
//
#include <hip/hip_runtime.h>
#include <math.h>

#define HH 352
#define WW 352
#define INF_I (1 << 30)

// ---------------------------------------------------------------------------
// One flat kernel, one thread per pixel.
// d2 = min over opposite-valued pixels of (di^2+dj^2)  [== |sdt|^2 exactly:
// one of dist_fg/dist_bg is 0 at every pixel, the other is dist-to-opposite].
// 5x5 window scan (24 unconditional clamped coalesced loads) is EXACT when it
// hits (window best <= 8 < 9 <= any d2 outside); clamp-duplicates are always
// dominated by the same cell at smaller offset. Rare exact expanding-ring
// fallback (P ~ 2^-24/pixel). w = exp(-sqrt(d2)/5); no-opposite => w=0
// (matches reference: exp(-sqrt(1e10)/5) underflows, and wn==0 either way).
// Then bce, and per-block reduce of (min w, max w, sum bce, sum bce*w):
// loss separability: sum bce*(1+0.5*wn) = S1 + 0.5*(SW - wmin*S1)/den.
// ---------------------------------------------------------------------------
__global__ __launch_bounds__(256) void fused2d_kernel(const float* __restrict__ pred,
                                                      const float* __restrict__ target,
                                                      float* __restrict__ bmin,
                                                      float* __restrict__ bmax,
                                                      float* __restrict__ bs1,
                                                      float* __restrict__ bsw)
{
    const int HW = HH * WW;
    int idx = blockIdx.x * 256 + threadIdx.x;
    int b = idx / HW;
    int r0 = idx - b * HW;
    int i = r0 / WW;
    int j = r0 - i * WW;
    const float* timg = target + b * HW;

    float p = pred[idx];                    // hoisted: latency overlaps window burst
    bool fg = (timg[i * WW + j] != 0.0f);

    int best = INF_I;
    #pragma unroll
    for (int dy = -2; dy <= 2; ++dy) {
        int iy = i + dy; iy = iy < 0 ? 0 : (iy >= HH ? HH - 1 : iy);
        int rowo = iy * WW;
        #pragma unroll
        for (int dx = -2; dx <= 2; ++dx) {
            if (dy == 0 && dx == 0) continue;
            int jx = j + dx; jx = jx < 0 ? 0 : (jx >= WW ? WW - 1 : jx);
            float v = timg[rowo + jx];
            bool opp = (v != 0.0f) != fg;
            int cand = dy * dy + dx * dx;   // compile-time constant per unrolled iter
            best = (opp && cand < best) ? cand : best;
        }
    }

    if (best == INF_I) {                    // rare exact fallback (P ~ 2^-24/pixel)
        for (int rad = 3; rad <= 351; ++rad) {
            if (rad * rad >= best) break;   // ring-rad cells have d2 >= rad^2
            int y0 = i - rad, y1 = i + rad, x0 = j - rad, x1 = j + rad;
            int xa = x0 < 0 ? 0 : x0, xb = x1 >= WW ? WW - 1 : x1;
            for (int pass = 0; pass < 2; ++pass) {       // top & bottom rows
                int iy = pass ? y1 : y0;
                if (iy < 0 || iy >= HH) continue;
                int dy2 = (iy - i) * (iy - i);
                for (int jx = xa; jx <= xb; ++jx) {
                    if ((timg[iy * WW + jx] != 0.0f) != fg) {
                        int cd = dy2 + (jx - j) * (jx - j);
                        if (cd < best) best = cd;
                    }
                }
            }
            int ya = y0 + 1 < 0 ? 0 : y0 + 1, yb = y1 - 1 >= HH ? HH - 1 : y1 - 1;
            for (int pass = 0; pass < 2; ++pass) {       // left & right cols
                int jx = pass ? x1 : x0;
                if (jx < 0 || jx >= WW) continue;
                int dx2 = (jx - j) * (jx - j);
                for (int iy = ya; iy <= yb; ++iy) {
                    if ((timg[iy * WW + jx] != 0.0f) != fg) {
                        int cd = dx2 + (iy - i) * (iy - i);
                        if (cd < best) best = cd;
                    }
                }
            }
        }
    }

    float w = (best == INF_I) ? 0.0f : expf(-sqrtf((float)best) * 0.2f);  // SIGMA=5
    float t = fg ? 1.0f : 0.0f;             // target is exactly {0,1}
    float bce = fmaxf(p, 0.0f) - p * t + log1pf(expf(-fabsf(p)));
    float bw = bce * w;

    // block reduce (4 waves): min w, max w, sum bce, sum bce*w
    float lmin = w, lmax = w, ls1 = bce, lsw = bw;
    #pragma unroll
    for (int off = 32; off > 0; off >>= 1) {
        lmin = fminf(lmin, __shfl_down(lmin, off));
        lmax = fmaxf(lmax, __shfl_down(lmax, off));
        ls1 += __shfl_down(ls1, off);
        lsw += __shfl_down(lsw, off);
    }
    __shared__ float s4[4][4];
    int wid = threadIdx.x >> 6;
    if ((threadIdx.x & 63) == 0) {
        s4[0][wid] = lmin; s4[1][wid] = lmax; s4[2][wid] = ls1; s4[3][wid] = lsw;
    }
    __syncthreads();
    if (threadIdx.x == 0) {
        float m0 = s4[0][0], m1 = s4[1][0], a = s4[2][0], c2 = s4[3][0];
        #pragma unroll
        for (int q = 1; q < 4; ++q) {
            m0 = fminf(m0, s4[0][q]);
            m1 = fmaxf(m1, s4[1][q]);
            a += s4[2][q];
            c2 += s4[3][q];
        }
        bmin[blockIdx.x] = m0; bmax[blockIdx.x] = m1;
        bs1[blockIdx.x] = a;   bsw[blockIdx.x] = c2;
    }
}

// ---------------------------------------------------------------------------
// Final: 1 block, wave wv handles sample wv (+4 strides). Per sample: reduce
// nPB per-block entries -> wmin, wmax, S1, SW (f64 sums), combine
// loss_b = S1 + 0.5*(SW - wmin*S1)/den; sum across samples; mean -> out.
// ---------------------------------------------------------------------------
__global__ __launch_bounds__(256) void final2_kernel(const float* __restrict__ bmin,
                                                     const float* __restrict__ bmax,
                                                     const float* __restrict__ bs1,
                                                     const float* __restrict__ bsw,
                                                     float* __restrict__ out,
                                                     int B, int nPB, double invN)
{
    __shared__ double sl[4];
    int wid = threadIdx.x >> 6, lane = threadIdx.x & 63;
    double mysum = 0.0;
    for (int b = wid; b < B; b += 4) {
        float lmin = 3e38f, lmax = 0.0f;
        double ds1 = 0.0, dsw = 0.0;
        for (int t = lane; t < nPB; t += 64) {
            int o = b * nPB + t;
            lmin = fminf(lmin, bmin[o]);
            lmax = fmaxf(lmax, bmax[o]);
            ds1 += (double)bs1[o];
            dsw += (double)bsw[o];
        }
        #pragma unroll
        for (int off = 32; off > 0; off >>= 1) {
            lmin = fminf(lmin, __shfl_down(lmin, off));
            lmax = fmaxf(lmax, __shfl_down(lmax, off));
            ds1 += __shfl_down(ds1, off);
            dsw += __shfl_down(dsw, off);
        }
        if (lane == 0) {
            double wmin = (double)lmin;
            double den  = (double)lmax - wmin + 1e-6;
            mysum += ds1 + 0.5 * (dsw - wmin * ds1) / den;
        }
    }
    if (lane == 0) sl[wid] = mysum;
    __syncthreads();
    if (threadIdx.x == 0) {
        double tot = 0.0;
        #pragma unroll
        for (int q = 0; q < 4; ++q) tot += sl[q];
        out[0] = (float)(tot * invN);
    }
}

extern "C" void kernel_launch(void* const* d_in, const int* in_sizes, int n_in,
                              void* d_out, int out_size, void* d_ws, size_t ws_size,
                              hipStream_t stream)
{
    const float* pred   = (const float*)d_in[0];
    const float* target = (const float*)d_in[1];
    float* out = (float*)d_out;

    const int N = in_sizes[0];           // B*1*H*W = 495616
    const int B = N / (HH * WW);         // = 4
    const int nBlk = N / 256;            // 1936, exact
    const int nPB = (HH * WW) / 256;     // 484 blocks per sample (block-uniform)

    float* bmin = (float*)d_ws;
    float* bmax = bmin + nBlk;
    float* bs1  = bmax + nBlk;
    float* bsw  = bs1 + nBlk;

    hipLaunchKernelGGL(fused2d_kernel, dim3(nBlk), dim3(256), 0, stream,
                       pred, target, bmin, bmax, bs1, bsw);

    hipLaunchKernelGGL(final2_kernel, dim3(1), dim3(256), 0, stream,
                       bmin, bmax, bs1, bsw, out, B, nPB, 1.0 / (double)N);
}